// Round 5
// baseline (289.880 us; speedup 1.0000x reference)
//
#include <hip/hip_runtime.h>
#include <hip/hip_bf16.h>

#define NN 50000   // nodes
#define HID 256    // hidden
#define NE 800000  // edges

typedef unsigned short u16;
typedef __attribute__((ext_vector_type(8))) short short8v;  // 8 bf16 = 4 VGPRs
typedef __attribute__((ext_vector_type(4))) float f32x4;

__device__ __forceinline__ u16 f2bf(float v) {
    __hip_bfloat16 h = __float2bfloat16(v);
    return *reinterpret_cast<u16*>(&h);
}

// ---------------------------------------------------------------------------
// Prep: W1b[kbg][j][kk] bf16, kbg in [0,32), j in [0,512), kk in [0,8).
// B[k][j] = W1[k + (j>=256)*256][j&255], k = kbg*8+kk.
// Exactly the MFMA B-fragment feed order: a b-fragment for (k-block kbg,
// col j) is the contiguous 16B at W1b[(kbg*512+j)*8].
// ---------------------------------------------------------------------------
__global__ __launch_bounds__(256)
void prep_w1b(const float* __restrict__ W1, u16* __restrict__ W1b) {
    const int idx = blockIdx.x * 256 + threadIdx.x;   // 32*512 = 16384
    if (idx >= 32 * 512) return;
    const int kbg  = idx >> 9;
    const int j    = idx & 511;
    const int row0 = (j >= HID) ? HID : 0;
    const int col  = j & (HID - 1);
    u16 o[8];
    #pragma unroll
    for (int kk = 0; kk < 8; ++kk) {
        const int k = kbg * 8 + kk;
        o[kk] = f2bf(W1[(size_t)(row0 + k) * HID + col]);
    }
    *(uint4*)(W1b + (size_t)idx * 8) = *(uint4*)o;
}

// ---------------------------------------------------------------------------
// Kernel 1 (MFMA, zero-LDS main loop):
// P[M=50000, N=512] = A[M,256] x B[256,512]  (+b1 on j<256), bf16 out.
// Block = 4 waves, BM=64 (16 rows per wave). Each wave:
//   - loads its 16 rows x full K=256 of z as 8 A-fragments (32 VGPRs), once
//   - for each of 4 j-tiles (128 cols): 8 K-steps x 8 MFMA, B-fragments
//     loaded directly from W1b (256KB, L1/L2-resident, shared across waves)
//   - epilogue via per-wave-private LDS region -> coalesced 16B stores
// ---------------------------------------------------------------------------
#define LDE 136   // epilogue row stride in u16 (272B: 16B-aligned rows)

__global__ __launch_bounds__(256)
void node_gemm(const float* __restrict__ z, const u16* __restrict__ W1b,
               const float* __restrict__ b1, u16* __restrict__ P) {
    __shared__ __align__(16) u16 lds[64 * LDE];   // 17408 B

    const int tid  = threadIdx.x;
    const int lane = tid & 63;
    const int w    = tid >> 6;            // wave 0..3
    const int l16  = lane & 15;
    const int l4   = lane >> 4;           // k-block within K-step
    const int m0   = blockIdx.x * 64;
    const int row  = m0 + w * 16 + l16;   // this lane's A row (frag row = l16)

    // ---- load all A-fragments for K=256 (once) ----
    short8v af[8];
    const bool rowok = (row < NN);
    const float* zr = z + (size_t)row * HID;
    #pragma unroll
    for (int ks = 0; ks < 8; ++ks) {
        float4 v0 = make_float4(0.f, 0.f, 0.f, 0.f), v1 = v0;
        if (rowok) {
            v0 = *(const float4*)(zr + ks * 32 + l4 * 8);
            v1 = *(const float4*)(zr + ks * 32 + l4 * 8 + 4);
        }
        u16 t[8] = { f2bf(v0.x), f2bf(v0.y), f2bf(v0.z), f2bf(v0.w),
                     f2bf(v1.x), f2bf(v1.y), f2bf(v1.z), f2bf(v1.w) };
        af[ks] = *(short8v*)t;
    }

    for (int jt = 0; jt < 4; ++jt) {
        f32x4 acc[8] = {};
        const u16* bbase = W1b + ((size_t)l4 * 512 + jt * 128 + l16) * 8;
        #pragma unroll
        for (int ks = 0; ks < 8; ++ks) {
            #pragma unroll
            for (int ni = 0; ni < 8; ++ni) {
                const short8v b = *(const short8v*)(bbase + ((size_t)ks * 4 * 512 + ni * 16) * 8);
                acc[ni] = __builtin_amdgcn_mfma_f32_16x16x32_bf16(af[ks], b, acc[ni], 0, 0, 0);
            }
        }

        // ---- epilogue: +b1 (cols<256), bf16, per-wave-private LDS rows ----
        #pragma unroll
        for (int ni = 0; ni < 8; ++ni) {
            const float bias = (jt < 2) ? b1[jt * 128 + ni * 16 + l16] : 0.f;
            #pragma unroll
            for (int r = 0; r < 4; ++r)
                lds[(w * 16 + l4 * 4 + r) * LDE + ni * 16 + l16] =
                    f2bf(acc[ni][r] + bias);
        }
        // copy-out: lane -> row w*16 + (lane>>2), 32 u16 at col (lane&3)*32
        const int crow = w * 16 + (lane >> 2);
        const int ccol = (lane & 3) * 32;
        const int gm   = m0 + crow;
        if (gm < NN) {
            u16* dst = P + (size_t)gm * 512 + jt * 128 + ccol;
            #pragma unroll
            for (int q = 0; q < 4; ++q)
                *(uint4*)(dst + q * 8) = *(uint4*)&lds[crow * LDE + ccol + q * 8];
        }
    }
}

// ---------------------------------------------------------------------------
// Kernel 2: out[e] = b2 + sum_h relu(P[src][h] + P[dst][256+h]) * W2[h]
// 16 lanes per edge (4 edges/wave), 16 features/lane, W2 cached in regs.
// ---------------------------------------------------------------------------
__device__ __forceinline__ void proc_pair(unsigned int ua, unsigned int ub,
                                          float w0, float w1, float& s) {
    const float a0 = __uint_as_float(ua << 16);
    const float a1 = __uint_as_float(ua & 0xffff0000u);
    const float b0 = __uint_as_float(ub << 16);
    const float b1 = __uint_as_float(ub & 0xffff0000u);
    const float x0 = fmaxf(a0 + b0, 0.f);
    const float x1 = fmaxf(a1 + b1, 0.f);
    s = fmaf(x0, w0, s);
    s = fmaf(x1, w1, s);
}

__global__ __launch_bounds__(256)
void edge_kernel(const int* __restrict__ ei, const u16* __restrict__ P,
                 const float* __restrict__ W2, const float* __restrict__ b2,
                 float* __restrict__ out) {
    const int lane = threadIdx.x & 63;
    const int sub  = lane >> 4;          // edge within wave (0..3)
    const int l16  = lane & 15;
    const int h0   = l16 * 16;           // this lane's 16 features

    float w[16];
    #pragma unroll
    for (int i = 0; i < 16; i += 4) {
        const float4 v = *(const float4*)(W2 + h0 + i);
        w[i] = v.x; w[i + 1] = v.y; w[i + 2] = v.z; w[i + 3] = v.w;
    }
    const float bias2 = b2[0];

    const int gwave   = (blockIdx.x * blockDim.x + threadIdx.x) >> 6;
    const int nwaves  = (gridDim.x * blockDim.x) >> 6;
    const int ngroups = NE >> 2;

    for (int g = gwave; g < ngroups; g += nwaves) {
        const int e   = g * 4 + sub;
        const int src = ei[e];
        const int dst = ei[NE + e];

        const u16* pa = P + (size_t)src * 512 + h0;
        const u16* pb = P + (size_t)dst * 512 + 256 + h0;
        const uint4 ta0 = *(const uint4*)(pa);
        const uint4 ta1 = *(const uint4*)(pa + 8);
        const uint4 tb0 = *(const uint4*)(pb);
        const uint4 tb1 = *(const uint4*)(pb + 8);

        float s = 0.f;
        proc_pair(ta0.x, tb0.x, w[0],  w[1],  s);
        proc_pair(ta0.y, tb0.y, w[2],  w[3],  s);
        proc_pair(ta0.z, tb0.z, w[4],  w[5],  s);
        proc_pair(ta0.w, tb0.w, w[6],  w[7],  s);
        proc_pair(ta1.x, tb1.x, w[8],  w[9],  s);
        proc_pair(ta1.y, tb1.y, w[10], w[11], s);
        proc_pair(ta1.z, tb1.z, w[12], w[13], s);
        proc_pair(ta1.w, tb1.w, w[14], w[15], s);

        s += __shfl_xor(s, 1);
        s += __shfl_xor(s, 2);
        s += __shfl_xor(s, 4);
        s += __shfl_xor(s, 8);
        if (l16 == 0) out[e] = s + bias2;
    }
}

// ---------------------------------------------------------------------------
extern "C" void kernel_launch(void* const* d_in, const int* in_sizes, int n_in,
                              void* d_out, int out_size, void* d_ws, size_t ws_size,
                              hipStream_t stream) {
    const float* z  = (const float*)d_in[0];
    const int*   ei = (const int*)d_in[1];
    const float* W1 = (const float*)d_in[2];
    const float* b1 = (const float*)d_in[3];
    const float* W2 = (const float*)d_in[4];
    const float* b2 = (const float*)d_in[5];
    float* out = (float*)d_out;

    u16* W1b = (u16*)d_ws;                 // 256 KB, fragment-layout bf16 B
    u16* P   = (u16*)d_ws + 131072;        // [NN][512] bf16 partials

    prep_w1b<<<64, 256, 0, stream>>>(W1, W1b);

    node_gemm<<<(NN + 63) / 64, 256, 0, stream>>>(z, W1b, b1, P);

    edge_kernel<<<2048, 256, 0, stream>>>(ei, P, W2, b2, out);
}

// Round 6
// 240.679 us; speedup vs baseline: 1.2044x; 1.2044x over previous
//
#include <hip/hip_runtime.h>
#include <hip/hip_bf16.h>

#define NN 50000   // nodes
#define HID 256    // hidden
#define NE 800000  // edges

typedef unsigned short u16;
typedef __attribute__((ext_vector_type(8))) short short8v;  // 8 bf16 = 4 VGPRs
typedef __attribute__((ext_vector_type(4))) float f32x4;

__device__ __forceinline__ u16 f2bf(float v) {
    __hip_bfloat16 h = __float2bfloat16(v);
    return *reinterpret_cast<u16*>(&h);
}

// ---------------------------------------------------------------------------
// Prep: W1b half-major fragment layout.
// Granule g = h*8192 + kbg*256 + jh   (h: col-half, kbg: k-group of 8, jh: col
// within half). Granule content kk=0..7: bf16 of W1[h*256 + kbg*8 + kk][jh].
// A block's B-half is then granules [h*8192, h*8192+8192) — a LINEAR 128KB
// run, so the LDS fill is a straight coalesced uint4 copy.
// ---------------------------------------------------------------------------
__global__ __launch_bounds__(256)
void prep_w1b(const float* __restrict__ W1, u16* __restrict__ W1b) {
    const int g = blockIdx.x * 256 + threadIdx.x;   // 0..16383
    if (g >= 2 * 32 * 256) return;
    const int h   = g >> 13;
    const int kbg = (g >> 8) & 31;
    const int jh  = g & 255;
    u16 o[8];
    #pragma unroll
    for (int kk = 0; kk < 8; ++kk)
        o[kk] = f2bf(W1[(size_t)(h * 256 + kbg * 8 + kk) * HID + jh]);
    *(uint4*)(W1b + (size_t)g * 8) = *(uint4*)o;
}

// ---------------------------------------------------------------------------
// Kernel 1 (MFMA, block-resident B in LDS):
// P[50000, 512] = A[50000,256] x B[256,512] (+b1 on cols<256), bf16 out.
// Grid = 196 blocks x 512 threads (8 waves), single wavefront-round.
// Each block: 256 rows. Each wave: 32 rows (M-block 2), all 256 cols of the
// current B-half. B-half (128KB, fragment layout) staged into LDS once,
// re-staged once for the second half; A held in VGPRs for the whole kernel.
// ---------------------------------------------------------------------------
__global__ __launch_bounds__(512)
void node_gemm(const float* __restrict__ z, const u16* __restrict__ W1b,
               const float* __restrict__ b1, u16* __restrict__ P) {
    __shared__ __align__(16) u16 Blds[32 * 256 * 8];   // 131072 B

    const int tid  = threadIdx.x;
    const int lane = tid & 63;
    const int w    = tid >> 6;            // wave 0..7
    const int l16  = lane & 15;
    const int l4   = lane >> 4;           // k-subgroup 0..3
    const int r0   = blockIdx.x * 256 + w * 32;

    // ---- A fragments: 2 m-frags x 8 k-steps, loaded once (z read ONCE) ----
    short8v af[2][8];
    #pragma unroll
    for (int mi = 0; mi < 2; ++mi) {
        const int row = r0 + mi * 16 + l16;
        const bool ok = (row < NN);
        const float* zr = z + (size_t)row * HID;
        #pragma unroll
        for (int ks = 0; ks < 8; ++ks) {
            float4 v0 = make_float4(0.f, 0.f, 0.f, 0.f), v1 = v0;
            if (ok) {
                v0 = *(const float4*)(zr + ks * 32 + l4 * 8);
                v1 = *(const float4*)(zr + ks * 32 + l4 * 8 + 4);
            }
            u16 t[8] = { f2bf(v0.x), f2bf(v0.y), f2bf(v0.z), f2bf(v0.w),
                         f2bf(v1.x), f2bf(v1.y), f2bf(v1.z), f2bf(v1.w) };
            af[mi][ks] = *(short8v*)t;
        }
    }

    const uint4* Wu4 = (const uint4*)W1b;
    uint4* Lu4 = (uint4*)Blds;

    #pragma unroll
    for (int h = 0; h < 2; ++h) {
        if (h) __syncthreads();           // all waves done reading half 0
        // ---- fill: linear coalesced copy of this half's 8192 granules ----
        #pragma unroll
        for (int c = 0; c < 16; ++c)
            Lu4[c * 512 + tid] = Wu4[(size_t)h * 8192 + c * 512 + tid];
        __syncthreads();

        #pragma unroll
        for (int ni = 0; ni < 16; ++ni) {
            f32x4 acc[2] = {};
            #pragma unroll
            for (int ks = 0; ks < 8; ++ks) {
                const short8v b = *(const short8v*)
                    &Blds[((ks * 4 + l4) * 256 + ni * 16 + l16) * 8];
                #pragma unroll
                for (int mi = 0; mi < 2; ++mi)
                    acc[mi] = __builtin_amdgcn_mfma_f32_16x16x32_bf16(
                        af[mi][ks], b, acc[mi], 0, 0, 0);
            }
            // ---- epilogue: +b1 (half 0 only), scalar bf16 stores ----
            const int col  = h * 256 + ni * 16 + l16;
            const float bias = (h == 0) ? b1[ni * 16 + l16] : 0.f;
            #pragma unroll
            for (int mi = 0; mi < 2; ++mi) {
                #pragma unroll
                for (int r = 0; r < 4; ++r) {
                    const int row = r0 + mi * 16 + l4 * 4 + r;
                    if (row < NN)
                        P[(size_t)row * 512 + col] = f2bf(acc[mi][r] + bias);
                }
            }
        }
    }
}

// ---------------------------------------------------------------------------
// Kernel 2: out[e] = b2 + sum_h relu(P[src][h] + P[dst][256+h]) * W2[h]
// 16 lanes per edge (4 edges/wave), 16 features/lane, W2 cached in regs.
// ---------------------------------------------------------------------------
__device__ __forceinline__ void proc_pair(unsigned int ua, unsigned int ub,
                                          float w0, float w1, float& s) {
    const float a0 = __uint_as_float(ua << 16);
    const float a1 = __uint_as_float(ua & 0xffff0000u);
    const float b0 = __uint_as_float(ub << 16);
    const float b1 = __uint_as_float(ub & 0xffff0000u);
    const float x0 = fmaxf(a0 + b0, 0.f);
    const float x1 = fmaxf(a1 + b1, 0.f);
    s = fmaf(x0, w0, s);
    s = fmaf(x1, w1, s);
}

__global__ __launch_bounds__(256)
void edge_kernel(const int* __restrict__ ei, const u16* __restrict__ P,
                 const float* __restrict__ W2, const float* __restrict__ b2,
                 float* __restrict__ out) {
    const int lane = threadIdx.x & 63;
    const int sub  = lane >> 4;          // edge within wave (0..3)
    const int l16  = lane & 15;
    const int h0   = l16 * 16;           // this lane's 16 features

    float w[16];
    #pragma unroll
    for (int i = 0; i < 16; i += 4) {
        const float4 v = *(const float4*)(W2 + h0 + i);
        w[i] = v.x; w[i + 1] = v.y; w[i + 2] = v.z; w[i + 3] = v.w;
    }
    const float bias2 = b2[0];

    const int gwave   = (blockIdx.x * blockDim.x + threadIdx.x) >> 6;
    const int nwaves  = (gridDim.x * blockDim.x) >> 6;
    const int ngroups = NE >> 2;

    for (int g = gwave; g < ngroups; g += nwaves) {
        const int e   = g * 4 + sub;
        const int src = ei[e];
        const int dst = ei[NE + e];

        const u16* pa = P + (size_t)src * 512 + h0;
        const u16* pb = P + (size_t)dst * 512 + 256 + h0;
        const uint4 ta0 = *(const uint4*)(pa);
        const uint4 ta1 = *(const uint4*)(pa + 8);
        const uint4 tb0 = *(const uint4*)(pb);
        const uint4 tb1 = *(const uint4*)(pb + 8);

        float s = 0.f;
        proc_pair(ta0.x, tb0.x, w[0],  w[1],  s);
        proc_pair(ta0.y, tb0.y, w[2],  w[3],  s);
        proc_pair(ta0.z, tb0.z, w[4],  w[5],  s);
        proc_pair(ta0.w, tb0.w, w[6],  w[7],  s);
        proc_pair(ta1.x, tb1.x, w[8],  w[9],  s);
        proc_pair(ta1.y, tb1.y, w[10], w[11], s);
        proc_pair(ta1.z, tb1.z, w[12], w[13], s);
        proc_pair(ta1.w, tb1.w, w[14], w[15], s);

        s += __shfl_xor(s, 1);
        s += __shfl_xor(s, 2);
        s += __shfl_xor(s, 4);
        s += __shfl_xor(s, 8);
        if (l16 == 0) out[e] = s + bias2;
    }
}

// ---------------------------------------------------------------------------
extern "C" void kernel_launch(void* const* d_in, const int* in_sizes, int n_in,
                              void* d_out, int out_size, void* d_ws, size_t ws_size,
                              hipStream_t stream) {
    const float* z  = (const float*)d_in[0];
    const int*   ei = (const int*)d_in[1];
    const float* W1 = (const float*)d_in[2];
    const float* b1 = (const float*)d_in[3];
    const float* W2 = (const float*)d_in[4];
    const float* b2 = (const float*)d_in[5];
    float* out = (float*)d_out;

    u16* W1b = (u16*)d_ws;                 // 256 KB, half-major fragment layout
    u16* P   = (u16*)d_ws + 131072;        // [NN][512] bf16 partials

    prep_w1b<<<64, 256, 0, stream>>>(W1, W1b);

    node_gemm<<<196, 512, 0, stream>>>(z, W1b, b1, P);

    edge_kernel<<<2048, 256, 0, stream>>>(ei, P, W2, b2, out);
}